// Round 2
// baseline (329.983 us; speedup 1.0000x reference)
//
#include <hip/hip_runtime.h>

// DispCorr: out[b,d,h,w] = (1/C) * sum_c L[b,c,h,w] * R[b,c,h,w-d], w-d<0 -> 0
// x: (4, 64, 256, 512) fp32; L = x[:, :32], R = x[:, 32:]; out: (4, 64, 256, 512) fp32
#define BB  4
#define CC  32
#define HH  256
#define WW  512
#define DD  64
#define PAD 64
#define ROWF (WW + PAD)          // 576 floats per LDS row (pad region [0,64) is zeros)
#define CSTRIDE ((size_t)HH * WW)  // channel stride in x = 131072 floats

__global__ __launch_bounds__(256, 2)
void disp_corr_kernel(const float* __restrict__ x, float* __restrict__ out) {
    __shared__ float Rsm[CC][ROWF];

    const int bid = blockIdx.x;
    const int b   = bid >> 8;    // /HH
    const int h   = bid & 255;   // %HH
    const int tid = threadIdx.x;

    // ---- stage R row (channels 32..63) into LDS, with leading zero pad ----
    const float* Rbase = x + (((size_t)b * 64 + CC) * HH + h) * WW;

    // zero pad: Rsm[c][0..63] = 0   (covers w-d < 0)
    for (int i = tid; i < CC * PAD; i += 256)
        Rsm[i >> 6][i & 63] = 0.0f;

    // main data: 32 rows x 512 floats = 4096 float4, coalesced
    for (int i = tid; i < CC * WW / 4; i += 256) {
        const int c = i >> 7;              // 128 float4 per row
        const int w = (i & 127) << 2;
        const float4 v = *(const float4*)(Rbase + (size_t)c * CSTRIDE + w);
        *(float4*)&Rsm[c][PAD + w] = v;
    }
    __syncthreads();

    // ---- each thread: w0 = 2*tid, all 64 disparities ----
    const int w0 = tid << 1;
    const float* Lrow = x + (((size_t)b * 64) * HH + h) * WW + w0;
    const float inv_c = 1.0f / (float)CC;   // 1/32, exact power of two

    float acc0[DD], acc1[DD];
    #pragma unroll
    for (int d = 0; d < DD; ++d) { acc0[d] = 0.0f; acc1[d] = 0.0f; }

    // c-loop in chunks of 4 with one-chunk-ahead global prefetch of L
    float2 lc[4], ln[4];
    #pragma unroll
    for (int k = 0; k < 4; ++k)
        lc[k] = *(const float2*)(Lrow + (size_t)k * CSTRIDE);

    for (int c4 = 0; c4 < CC / 4; ++c4) {
        #pragma unroll
        for (int k = 0; k < 4; ++k) ln[k] = make_float2(0.0f, 0.0f);
        if (c4 + 1 < CC / 4) {
            #pragma unroll
            for (int k = 0; k < 4; ++k)
                ln[k] = *(const float2*)(Lrow + (size_t)(c4 * 4 + 4 + k) * CSTRIDE);
        }

        #pragma unroll
        for (int k = 0; k < 4; ++k) {
            const int c = c4 * 4 + k;
            const float l0 = lc[k].x * inv_c;
            const float l1 = lc[k].y * inv_c;

            // r_d = Rsm[c][PAD + w0 - d].  For even e, the aligned float2 at
            // dword (PAD + w0 - e) is (r_e, r_{e-1}) -- exactly the operand
            // pair for disparity e; the next pair serves e+1.
            const float* rrow = &Rsm[c][0];
            float2 P = *(const float2*)(rrow + PAD + w0);       // (r_0, r_{-1})
            #pragma unroll
            for (int d = 0; d < DD; d += 2) {
                const float2 Pn = *(const float2*)(rrow + PAD + w0 - d - 2); // (r_{d+2}, r_{d+1})
                acc0[d]     += l0 * P.x;    // r_d
                acc1[d]     += l1 * P.y;    // r_{d-1}
                acc0[d + 1] += l0 * Pn.y;   // r_{d+1}
                acc1[d + 1] += l1 * P.x;    // r_d
                P = Pn;
            }
        }
        #pragma unroll
        for (int k = 0; k < 4; ++k) lc[k] = ln[k];
    }

    // ---- write out: out[b][d][h][w0..w0+1] ----
    float* orow = out + ((size_t)b * DD * HH + h) * WW + w0;
    #pragma unroll
    for (int d = 0; d < DD; ++d) {
        float2 v; v.x = acc0[d]; v.y = acc1[d];
        *(float2*)(orow + (size_t)d * CSTRIDE) = v;
    }
}

extern "C" void kernel_launch(void* const* d_in, const int* in_sizes, int n_in,
                              void* d_out, int out_size, void* d_ws, size_t ws_size,
                              hipStream_t stream) {
    const float* x = (const float*)d_in[0];
    float* out = (float*)d_out;
    dim3 grid(BB * HH);   // 1024 blocks, one per (b, h)
    dim3 block(256);
    disp_corr_kernel<<<grid, block, 0, stream>>>(x, out);
}

// Round 3
// 279.353 us; speedup vs baseline: 1.1812x; 1.1812x over previous
//
#include <hip/hip_runtime.h>

// DispCorr: out[b,d,h,w] = (1/C) * sum_c L[b,c,h,w] * R[b,c,h,w-d], w-d<0 -> 0
// x: (4, 64, 256, 512) fp32; L = x[:, :32], R = x[:, 32:]; out: (4, 64, 256, 512) fp32
//
// Round-3 structure: 1 block per (b,h), 512 threads.
//   threads [0,256):   w0 = 2*tid,        d in [0,32)
//   threads [256,512): w0 = 2*(tid-256),  d in [32,64)
// 64 accumulator VGPRs per thread (no spill; round-2's 128-acc version spilled:
// VGPR_Count=128 with WRITE_SIZE 2.4x output size). LDS 72KB -> 2 blocks/CU
// = 16 waves/CU resident.
#define BB  4
#define CC  32
#define HH  256
#define WW  512
#define DD  64
#define PAD 64
#define ROWF (WW + PAD)            // 576 floats per LDS row; [0,64) is zeros
#define CSTRIDE ((size_t)HH * WW)  // channel stride in x = 131072 floats

__global__ __launch_bounds__(512, 4)
void disp_corr_kernel(const float* __restrict__ x, float* __restrict__ out) {
    __shared__ float Rsm[CC][ROWF];

    const int bid = blockIdx.x;
    const int b   = bid >> 8;    // /HH
    const int h   = bid & 255;   // %HH
    const int tid = threadIdx.x;

    // ---- stage R row (channels 32..63) into LDS, leading 64-float zero pad ----
    const float* Rbase = x + (((size_t)b * 64 + CC) * HH + h) * WW;

    for (int i = tid; i < CC * PAD; i += 512)
        Rsm[i >> 6][i & 63] = 0.0f;

    for (int i = tid; i < CC * WW / 4; i += 512) {
        const int c = i >> 7;              // 128 float4 per row
        const int w = (i & 127) << 2;
        *(float4*)&Rsm[c][PAD + w] = *(const float4*)(Rbase + (size_t)c * CSTRIDE + w);
    }
    __syncthreads();

    // ---- each thread: w0, w0+1 for 32 disparities [dbase, dbase+32) ----
    const int w0    = (tid & 255) << 1;
    const int dbase = (tid >> 8) << 5;     // 0 or 32
    const float* Lrow = x + (((size_t)b * 64) * HH + h) * WW + w0;
    const float inv_c = 1.0f / (float)CC;  // 1/32, exact

    float acc0[32], acc1[32];
    #pragma unroll
    for (int e = 0; e < 32; ++e) { acc0[e] = 0.0f; acc1[e] = 0.0f; }

    // c-loop in chunks of 4 with one-chunk-ahead global prefetch of L
    float2 lc[4], ln[4];
    #pragma unroll
    for (int k = 0; k < 4; ++k)
        lc[k] = *(const float2*)(Lrow + (size_t)k * CSTRIDE);

    for (int c4 = 0; c4 < CC / 4; ++c4) {
        #pragma unroll
        for (int k = 0; k < 4; ++k) ln[k] = make_float2(0.0f, 0.0f);
        if (c4 + 1 < CC / 4) {
            #pragma unroll
            for (int k = 0; k < 4; ++k)
                ln[k] = *(const float2*)(Lrow + (size_t)(c4 * 4 + 4 + k) * CSTRIDE);
        }

        #pragma unroll
        for (int k = 0; k < 4; ++k) {
            const int c = c4 * 4 + k;
            const float l0 = lc[k].x * inv_c;
            const float l1 = lc[k].y * inv_c;

            // Absolute disparity d = dbase + e.
            // Aligned float2 at dword (PAD + w0 - dbase - e), e even, is
            // (r[w0-d], r[w0-d+1]) -- operands for (w0,d) and (w0+1,d);
            // the next pair serves d+1. 17 ds_read_b64 feed 128 FMAs.
            const float* rrow = &Rsm[c][0];
            float2 P = *(const float2*)(rrow + PAD + w0 - dbase);  // (r[w0-dbase], r[w0-dbase+1])
            #pragma unroll
            for (int e = 0; e < 32; e += 2) {
                const float2 Pn = *(const float2*)(rrow + PAD + w0 - dbase - e - 2);
                acc0[e]     += l0 * P.x;    // r[w0-d]
                acc1[e]     += l1 * P.y;    // r[w0+1-d]
                acc0[e + 1] += l0 * Pn.y;   // r[w0-(d+1)]
                acc1[e + 1] += l1 * P.x;    // r[w0+1-(d+1)]
                P = Pn;
            }
        }
        #pragma unroll
        for (int k = 0; k < 4; ++k) lc[k] = ln[k];
    }

    // ---- write out: out[b][dbase+e][h][w0..w0+1] ----
    float* orow = out + (((size_t)b * DD + dbase) * HH + h) * WW + w0;
    #pragma unroll
    for (int e = 0; e < 32; ++e) {
        float2 v; v.x = acc0[e]; v.y = acc1[e];
        *(float2*)(orow + (size_t)e * CSTRIDE) = v;
    }
}

extern "C" void kernel_launch(void* const* d_in, const int* in_sizes, int n_in,
                              void* d_out, int out_size, void* d_ws, size_t ws_size,
                              hipStream_t stream) {
    const float* x = (const float*)d_in[0];
    float* out = (float*)d_out;
    dim3 grid(BB * HH);   // 1024 blocks, one per (b, h)
    dim3 block(512);
    disp_corr_kernel<<<grid, block, 0, stream>>>(x, out);
}

// Round 4
// 266.832 us; speedup vs baseline: 1.2367x; 1.0469x over previous
//
#include <hip/hip_runtime.h>

// DispCorr: out[b,d,h,w] = (1/C) * sum_c L[b,c,h,w] * R[b,c,h,w-d], w-d<0 -> 0
// x: (4, 64, 256, 512) fp32; L = x[:, :32], R = x[:, 32:]; out: (4, 64, 256, 512) fp32
//
// Round-4 structure: 1 block per (b,h), 1024 threads.
//   thread = (p, g): p = tid&127 -> w-quad w0=4p; g = tid>>7 -> d in [8g, 8g+8)
//   acc[8][4] = 32 VGPRs (r3's 64-acc version spilled: WRITE_SIZE was
//   output+103MB, extra writes proportional to acc count in r2/r3).
// Window for 8 d x 4 cols = 11 dwords [q-7, q+3], q = 64+w0-8g = 0 mod 4
//   -> exactly 3 aligned ds_read_b128 (independent addresses, batchable)
//   vs r3's 17 chained ds_read_b64.
#define BB  4
#define CC  32
#define HH  256
#define WW  512
#define DD  64
#define PAD 64
#define ROWF (WW + PAD)            // 576 floats per LDS row; [0,64) is zeros
#define CSTRIDE ((size_t)HH * WW)  // channel stride = 131072 floats

__global__ __launch_bounds__(1024, 4)
void disp_corr_kernel(const float* __restrict__ x, float* __restrict__ out) {
    __shared__ float Rsm[CC][ROWF];

    const int bid = blockIdx.x;
    const int b   = bid >> 8;    // /HH
    const int h   = bid & 255;   // %HH
    const int tid = threadIdx.x;

    // ---- stage R row (channels 32..63) into LDS, leading 64-float zero pad ----
    const float* Rbase = x + (((size_t)b * 64 + CC) * HH + h) * WW;

    #pragma unroll
    for (int i = tid; i < CC * PAD; i += 1024)          // 2 iters
        Rsm[i >> 6][i & 63] = 0.0f;

    #pragma unroll
    for (int i = tid; i < CC * WW / 4; i += 1024) {     // 4 iters, coalesced float4
        const int c = i >> 7;
        const int w = (i & 127) << 2;
        *(float4*)&Rsm[c][PAD + w] = *(const float4*)(Rbase + (size_t)c * CSTRIDE + w);
    }
    __syncthreads();

    // ---- each thread: cols w0..w0+3, disparities [dbase, dbase+8) ----
    const int p     = tid & 127;
    const int g     = tid >> 7;        // 0..7
    const int w0    = p << 2;
    const int dbase = g << 3;          // 0..56
    const int q     = PAD + w0 - dbase;   // in [8, 572], q % 4 == 0
    const float* Lrow = x + (((size_t)b * 64) * HH + h) * WW + w0;

    float acc[8][4];
    #pragma unroll
    for (int e = 0; e < 8; ++e)
        #pragma unroll
        for (int j = 0; j < 4; ++j) acc[e][j] = 0.0f;

    // 1-ahead L prefetch. c=31 prefetches channel 32 (=R channel 0): valid
    // memory, value discarded.
    float4 lv = *(const float4*)(Lrow);
    for (int c = 0; c < CC; ++c) {
        const float4 ln = *(const float4*)(Lrow + (size_t)(c + 1) * CSTRIDE);

        const float* rrow = &Rsm[c][0];
        const float4 F0 = *(const float4*)(rrow + q - 8);
        const float4 F1 = *(const float4*)(rrow + q - 4);
        const float4 F2 = *(const float4*)(rrow + q);
        // f[i] = Rsm[c][q - 8 + i];  value for (d=dbase+e, col w0+j) = f[8+j-e]
        const float f[12] = {F0.x, F0.y, F0.z, F0.w,
                             F1.x, F1.y, F1.z, F1.w,
                             F2.x, F2.y, F2.z, F2.w};
        const float l[4] = {lv.x, lv.y, lv.z, lv.w};

        #pragma unroll
        for (int e = 0; e < 8; ++e)
            #pragma unroll
            for (int j = 0; j < 4; ++j)
                acc[e][j] += l[j] * f[8 + j - e];

        lv = ln;
    }

    // ---- epilogue: scale by 1/32 (exact) and write float4 per disparity ----
    const float s = 1.0f / (float)CC;
    float* orow = out + (((size_t)b * DD + dbase) * HH + h) * WW + w0;
    #pragma unroll
    for (int e = 0; e < 8; ++e) {
        float4 v;
        v.x = acc[e][0] * s; v.y = acc[e][1] * s;
        v.z = acc[e][2] * s; v.w = acc[e][3] * s;
        *(float4*)(orow + (size_t)e * CSTRIDE) = v;
    }
}

extern "C" void kernel_launch(void* const* d_in, const int* in_sizes, int n_in,
                              void* d_out, int out_size, void* d_ws, size_t ws_size,
                              hipStream_t stream) {
    const float* x = (const float*)d_in[0];
    float* out = (float*)d_out;
    dim3 grid(BB * HH);   // 1024 blocks, one per (b, h)
    dim3 block(1024);
    disp_corr_kernel<<<grid, block, 0, stream>>>(x, out);
}

// Round 5
// 260.368 us; speedup vs baseline: 1.2674x; 1.0248x over previous
//
#include <hip/hip_runtime.h>

// DispCorr: out[b,d,h,w] = (1/C) * sum_c L[b,c,h,w] * R[b,c,h,w-d], w-d<0 -> 0
// x: (4, 64, 256, 512) fp32; L = x[:, :32], R = x[:, 32:]; out: (4, 64, 256, 512) fp32
//
// Round-5 structure: 1 block per (b,h), 512 threads.
//   thread = (p, g): p = tid&127 -> w0 = 4p (4 cols, lanes 16B-contiguous ->
//   conflict-free ds_read_b128); g = tid>>7 -> d in [16g, 16g+16).
//   acc[16][4] = 64 VGPRs. 5 ds_read_b128 feed 64 FMAs per channel.
// c-loop unrolled x2, 2-float4 L prefetch pair (reads up to channel 33 = R
// channel 1: valid memory, discarded). amdgpu_waves_per_eu(4,4): LDS 72KB
// caps us at 2 blocks/CU = 4 waves/SIMD anyway, so pin it and give the
// allocator the full 128-VGPR budget (r3/r4 showed occupancy-greedy
// allocation: 64-with-spills / 36 VGPRs, starving ILP).
#define BB  4
#define CC  32
#define HH  256
#define WW  512
#define DD  64
#define PAD 64
#define ROWF (WW + PAD)            // 576 floats per LDS row; [0,64) is zeros
#define CSTRIDE ((size_t)HH * WW)  // channel stride = 131072 floats

__global__ __launch_bounds__(512) __attribute__((amdgpu_waves_per_eu(4, 4)))
void disp_corr_kernel(const float* __restrict__ x, float* __restrict__ out) {
    __shared__ float Rsm[CC][ROWF];

    const int bid = blockIdx.x;
    const int b   = bid >> 8;    // /HH
    const int h   = bid & 255;   // %HH
    const int tid = threadIdx.x;

    const int p     = tid & 127;       // wave = one g, p contiguous 0..63 / 64..127
    const int g     = tid >> 7;        // 0..3
    const int w0    = p << 2;
    const int dbase = g << 4;          // 0,16,32,48
    const int q     = PAD + w0 - dbase;   // in [16, 572], q % 4 == 0

    // issue first L loads before the staging barrier (independent of LDS)
    const float* Lrow = x + (((size_t)b * 64) * HH + h) * WW + w0;
    float4 La = *(const float4*)(Lrow);
    float4 Lb = *(const float4*)(Lrow + CSTRIDE);

    // ---- stage R row (channels 32..63) into LDS, leading 64-float zero pad ----
    const float* Rbase = x + (((size_t)b * 64 + CC) * HH + h) * WW;
    #pragma unroll
    for (int i = tid; i < CC * PAD; i += 512)          // 4 iters
        Rsm[i >> 6][i & 63] = 0.0f;
    #pragma unroll
    for (int i = tid; i < CC * WW / 4; i += 512) {     // 8 iters, coalesced float4
        const int c = i >> 7;
        const int w = (i & 127) << 2;
        *(float4*)&Rsm[c][PAD + w] = *(const float4*)(Rbase + (size_t)c * CSTRIDE + w);
    }
    __syncthreads();

    float acc[16][4];
    #pragma unroll
    for (int e = 0; e < 16; ++e)
        #pragma unroll
        for (int j = 0; j < 4; ++j) acc[e][j] = 0.0f;

    // ---- main loop: channels in pairs, 2-ahead L prefetch ----
    for (int c = 0; c < CC; c += 2) {
        const float4 Ln0 = *(const float4*)(Lrow + (size_t)(c + 2) * CSTRIDE);
        const float4 Ln1 = *(const float4*)(Lrow + (size_t)(c + 3) * CSTRIDE);

        // channel c (operand La)
        {
            const float* rr = &Rsm[c][q - 16];         // 16B-aligned
            const float4 F0 = ((const float4*)rr)[0];
            const float4 F1 = ((const float4*)rr)[1];
            const float4 F2 = ((const float4*)rr)[2];
            const float4 F3 = ((const float4*)rr)[3];
            const float4 F4 = ((const float4*)rr)[4];
            // f[i] = Rsm[c][q-16+i]; value for (d=dbase+e, col w0+j) = f[16+j-e]
            const float f[20] = {F0.x,F0.y,F0.z,F0.w, F1.x,F1.y,F1.z,F1.w,
                                 F2.x,F2.y,F2.z,F2.w, F3.x,F3.y,F3.z,F3.w,
                                 F4.x,F4.y,F4.z,F4.w};
            const float l[4] = {La.x, La.y, La.z, La.w};
            #pragma unroll
            for (int e = 0; e < 16; ++e)
                #pragma unroll
                for (int j = 0; j < 4; ++j)
                    acc[e][j] += l[j] * f[16 + j - e];
        }
        // channel c+1 (operand Lb)
        {
            const float* rr = &Rsm[c + 1][q - 16];
            const float4 F0 = ((const float4*)rr)[0];
            const float4 F1 = ((const float4*)rr)[1];
            const float4 F2 = ((const float4*)rr)[2];
            const float4 F3 = ((const float4*)rr)[3];
            const float4 F4 = ((const float4*)rr)[4];
            const float f[20] = {F0.x,F0.y,F0.z,F0.w, F1.x,F1.y,F1.z,F1.w,
                                 F2.x,F2.y,F2.z,F2.w, F3.x,F3.y,F3.z,F3.w,
                                 F4.x,F4.y,F4.z,F4.w};
            const float l[4] = {Lb.x, Lb.y, Lb.z, Lb.w};
            #pragma unroll
            for (int e = 0; e < 16; ++e)
                #pragma unroll
                for (int j = 0; j < 4; ++j)
                    acc[e][j] += l[j] * f[16 + j - e];
        }
        La = Ln0;
        Lb = Ln1;
    }

    // ---- epilogue: scale by 1/32 (exact) and write float4 per disparity ----
    const float s = 1.0f / (float)CC;
    float* orow = out + (((size_t)b * DD + dbase) * HH + h) * WW + w0;
    #pragma unroll
    for (int e = 0; e < 16; ++e) {
        float4 v;
        v.x = acc[e][0] * s; v.y = acc[e][1] * s;
        v.z = acc[e][2] * s; v.w = acc[e][3] * s;
        *(float4*)(orow + (size_t)e * CSTRIDE) = v;
    }
}

extern "C" void kernel_launch(void* const* d_in, const int* in_sizes, int n_in,
                              void* d_out, int out_size, void* d_ws, size_t ws_size,
                              hipStream_t stream) {
    const float* x = (const float*)d_in[0];
    float* out = (float*)d_out;
    dim3 grid(BB * HH);   // 1024 blocks, one per (b, h)
    dim3 block(512);
    disp_corr_kernel<<<grid, block, 0, stream>>>(x, out);
}

// Round 6
// 259.406 us; speedup vs baseline: 1.2721x; 1.0037x over previous
//
#include <hip/hip_runtime.h>

// DispCorr: out[b,d,h,w] = (1/C) * sum_c L[b,c,h,w] * R[b,c,h,w-d], w-d<0 -> 0
// x: (4, 64, 256, 512) fp32; L = x[:, :32], R = x[:, 32:]; out: (4, 64, 256, 512) fp32
//
// Round-6: high-occupancy variant of r4's no-spill shape.
//   Block = (b, h, wseg): W split into two 256-wide segments, 64-float halo.
//   LDS 40KB -> 4 blocks/CU; 512 thr -> 32 waves/CU resident (r5 was ~11).
//   Thread = (p=tid&63 -> w0=wbase+4p; g=tid>>6 -> d in [8g,8g+8)).
//   acc[8][4]=32 VGPRs; 3 ds_read_b128 feed 32 FMAs per channel (r4 inner
//   shape: proven VGPR=36, zero spill). Allocator's occupancy-greed (r2-r5
//   gave 128/64/36/64 regs, spilling anything bigger) now aligns with design.
#define BB   4
#define CC   32
#define HH   256
#define WW   512
#define DD   64
#define WSEG 256
#define HALO 64
#define ROWF (WSEG + HALO)          // 320 floats per LDS row
#define CSTRIDE ((size_t)HH * WW)   // channel stride = 131072 floats

__global__ __launch_bounds__(512)
void disp_corr_kernel(const float* __restrict__ x, float* __restrict__ out) {
    __shared__ float Rsm[CC][ROWF];  // 40960 B

    const int bid  = blockIdx.x;
    const int b    = bid >> 9;           // /(HH*2)
    const int rem  = bid & 511;
    const int h    = rem >> 1;
    const int wseg = rem & 1;
    const int wbase = wseg << 8;         // 0 or 256
    const int tid  = threadIdx.x;

    // ---- stage Rsm[c][k] = R[c][wbase-64+k] (zero where index < 0) ----
    // 32 rows x 80 float4 = 2560 float4; 5 per thread. For wseg=1 the whole
    // range R[c][192:512] is valid contiguous memory; for wseg=0 the first
    // 16 float4 of each row (gw in [-64,0)) are zeros.
    const float* Rrow = x + (((size_t)b * 64 + CC) * HH + h) * WW;
    for (int i = tid; i < CC * (ROWF / 4); i += 512) {
        const int c  = i / (ROWF / 4);       // /80
        const int j  = (i - c * (ROWF / 4)) << 2;
        const int gw = wbase - HALO + j;     // global w of this float4
        float4 v;
        if (gw < 0) v = make_float4(0.f, 0.f, 0.f, 0.f);
        else        v = *(const float4*)(Rrow + (size_t)c * CSTRIDE + gw);
        *(float4*)&Rsm[c][j] = v;
    }
    __syncthreads();

    // ---- each thread: cols w0..w0+3, disparities [dbase, dbase+8) ----
    const int p     = tid & 63;          // lane; wave = one g
    const int g     = tid >> 6;          // 0..7
    const int w0    = wbase + (p << 2);
    const int dbase = g << 3;            // 0..56
    const int qloc  = HALO + (p << 2) - dbase;   // in [8,316], %4==0
    const float* Lrow = x + (((size_t)b * 64) * HH + h) * WW + w0;

    float acc[8][4];
    #pragma unroll
    for (int e = 0; e < 8; ++e)
        #pragma unroll
        for (int j = 0; j < 4; ++j) acc[e][j] = 0.0f;

    // 1-ahead L prefetch; c=31 prefetches channel 32 (=R ch 0): valid, discarded.
    float4 lv = *(const float4*)(Lrow);
    for (int c = 0; c < CC; ++c) {
        const float4 ln = *(const float4*)(Lrow + (size_t)(c + 1) * CSTRIDE);

        const float* rr = &Rsm[c][qloc - 8];     // 16B-aligned
        const float4 F0 = ((const float4*)rr)[0];
        const float4 F1 = ((const float4*)rr)[1];
        const float4 F2 = ((const float4*)rr)[2];
        // f[i] = Rsm[c][qloc-8+i]; value for (d=dbase+e, col w0+j) = f[8+j-e]
        const float f[12] = {F0.x,F0.y,F0.z,F0.w, F1.x,F1.y,F1.z,F1.w,
                             F2.x,F2.y,F2.z,F2.w};
        const float l[4] = {lv.x, lv.y, lv.z, lv.w};

        #pragma unroll
        for (int e = 0; e < 8; ++e)
            #pragma unroll
            for (int j = 0; j < 4; ++j)
                acc[e][j] += l[j] * f[8 + j - e];

        lv = ln;
    }

    // ---- epilogue: scale by 1/32 (exact) and write float4 per disparity ----
    const float s = 1.0f / (float)CC;
    float* orow = out + (((size_t)b * DD + dbase) * HH + h) * WW + w0;
    #pragma unroll
    for (int e = 0; e < 8; ++e) {
        float4 v;
        v.x = acc[e][0] * s; v.y = acc[e][1] * s;
        v.z = acc[e][2] * s; v.w = acc[e][3] * s;
        *(float4*)(orow + (size_t)e * CSTRIDE) = v;
    }
}

extern "C" void kernel_launch(void* const* d_in, const int* in_sizes, int n_in,
                              void* d_out, int out_size, void* d_ws, size_t ws_size,
                              hipStream_t stream) {
    const float* x = (const float*)d_in[0];
    float* out = (float*)d_out;
    dim3 grid(BB * HH * 2);   // 2048 blocks: (b, h, wseg)
    dim3 block(512);
    disp_corr_kernel<<<grid, block, 0, stream>>>(x, out);
}

// Round 7
// 250.248 us; speedup vs baseline: 1.3186x; 1.0366x over previous
//
#include <hip/hip_runtime.h>

// DispCorr: out[b,d,h,w] = (1/C) * sum_c L[b,c,h,w] * R[b,c,h,w-d], w-d<0 -> 0
// x: (4, 64, 256, 512) fp32; L = x[:, :32], R = x[:, 32:]; out: (4, 64, 256, 512) fp32
//
// Round-7: pure-LDS inner loop. r6's loop kept a global L load per channel;
// FETCH=70MB shows those partially miss to HBM (~900cy), and a 1-deep
// prefetch + 4 waves/SIMD covers only ~300cy -> latency-bound at 25% on
// every pipe. Fix: stage L in LDS as well (Lsm 32KB + Rsm 40KB = 72KB,
// 2 blocks/CU). Inner loop = 4 ds_read_b128 + 32 FMA, no global access;
// HBM latency is confined to the bulk staging phase (9 independent
// coalesced float4 loads/thread, overlapped by the co-resident block).
//   Block = (b, h, wseg); thread = (p=tid&63 -> 4 cols, g=tid>>6 -> 8 d).
//   acc[8][4]=32 VGPRs (r4/r6-proven no-spill shape).
#define BB    4
#define CC    32
#define HH    256
#define WW    512
#define DD    64
#define WSEG  256
#define HALO  64
#define RROWF (WSEG + HALO)          // 320 floats per R row in LDS
#define CSTRIDE ((size_t)HH * WW)    // channel stride = 131072 floats

__global__ __launch_bounds__(512)
void disp_corr_kernel(const float* __restrict__ x, float* __restrict__ out) {
    __shared__ float Rsm[CC][RROWF];   // 40960 B
    __shared__ float Lsm[CC][WSEG];    // 32768 B   (total 73728 B)

    const int bid   = blockIdx.x;
    const int b     = bid >> 9;          // /(HH*2)
    const int rem   = bid & 511;
    const int h     = rem >> 1;
    const int wseg  = rem & 1;
    const int wbase = wseg << 8;         // 0 or 256
    const int tid   = threadIdx.x;

    // ---- stage R: Rsm[c][k] = R[c][wbase-64+k], zeros for negative index ----
    // 32 rows x 80 float4 = 2560 float4, 5 per thread, coalesced.
    const float* Rrow = x + (((size_t)b * 64 + CC) * HH + h) * WW;
    for (int i = tid; i < CC * (RROWF / 4); i += 512) {
        const int c  = i / (RROWF / 4);      // /80
        const int j  = (i - c * (RROWF / 4)) << 2;
        const int gw = wbase - HALO + j;
        float4 v;
        if (gw < 0) v = make_float4(0.f, 0.f, 0.f, 0.f);
        else        v = *(const float4*)(Rrow + (size_t)c * CSTRIDE + gw);
        *(float4*)&Rsm[c][j] = v;
    }

    // ---- stage L: Lsm[c][j] = L[c][wbase+j] ----
    // 32 rows x 64 float4 = 2048 float4, 4 per thread; each wave loads one
    // full contiguous 1KB row.
    const float* Lbase = x + (((size_t)b * 64) * HH + h) * WW + wbase;
    #pragma unroll
    for (int k = 0; k < 4; ++k) {
        const int i = tid + k * 512;
        const int c = i >> 6;
        const int j = (i & 63) << 2;
        *(float4*)&Lsm[c][j] = *(const float4*)(Lbase + (size_t)c * CSTRIDE + j);
    }
    __syncthreads();

    // ---- each thread: cols w0..w0+3, disparities [dbase, dbase+8) ----
    const int p     = tid & 63;          // lane; wave = one d-group
    const int g     = tid >> 6;          // 0..7
    const int w0l   = p << 2;            // local col
    const int dbase = g << 3;            // 0..56
    const int qloc  = HALO + w0l - dbase;   // in [8,316], %4==0

    float acc[8][4];
    #pragma unroll
    for (int e = 0; e < 8; ++e)
        #pragma unroll
        for (int j = 0; j < 4; ++j) acc[e][j] = 0.0f;

    for (int c = 0; c < CC; ++c) {
        const float4 lv = *(const float4*)&Lsm[c][w0l];          // ds_read_b128
        const float* rr = &Rsm[c][qloc - 8];                     // 16B-aligned
        const float4 F0 = ((const float4*)rr)[0];
        const float4 F1 = ((const float4*)rr)[1];
        const float4 F2 = ((const float4*)rr)[2];
        // f[i] = Rsm[c][qloc-8+i]; value for (d=dbase+e, col w0+j) = f[8+j-e]
        const float f[12] = {F0.x,F0.y,F0.z,F0.w, F1.x,F1.y,F1.z,F1.w,
                             F2.x,F2.y,F2.z,F2.w};
        const float l[4] = {lv.x, lv.y, lv.z, lv.w};

        #pragma unroll
        for (int e = 0; e < 8; ++e)
            #pragma unroll
            for (int j = 0; j < 4; ++j)
                acc[e][j] += l[j] * f[8 + j - e];
    }

    // ---- epilogue: scale by 1/32 (exact) and write float4 per disparity ----
    const float s = 1.0f / (float)CC;
    float* orow = out + (((size_t)b * DD + dbase) * HH + h) * WW + wbase + w0l;
    #pragma unroll
    for (int e = 0; e < 8; ++e) {
        float4 v;
        v.x = acc[e][0] * s; v.y = acc[e][1] * s;
        v.z = acc[e][2] * s; v.w = acc[e][3] * s;
        *(float4*)(orow + (size_t)e * CSTRIDE) = v;
    }
}

extern "C" void kernel_launch(void* const* d_in, const int* in_sizes, int n_in,
                              void* d_out, int out_size, void* d_ws, size_t ws_size,
                              hipStream_t stream) {
    const float* x = (const float*)d_in[0];
    float* out = (float*)d_out;
    dim3 grid(BB * HH * 2);   // 2048 blocks: (b, h, wseg)
    dim3 block(512);
    disp_corr_kernel<<<grid, block, 0, stream>>>(x, out);
}